// Round 9
// baseline (127.411 us; speedup 1.0000x reference)
//
#include <hip/hip_runtime.h>
#include <hip/hip_bf16.h>

// DeConv2d = 32 per-channel MLPs (128->256->256->4) over 8192 px + 2x2 shuffle.
//
// R9 = R8 skeleton (resident W, 8 waves, 2 tiles, no spill) + three surgical cuts:
//  - k-major LDS layout [ks][m][32k], 4KB/ks, XOR slot^(m&3) on 16B slots:
//    bank-perfect b128 reads AND single-base + offset-imm addressing (VALU~0)
//  - bias-in-acc-init + v_cvt_pk_bf16_f32 epilogue (4 fmax + 2 cvt per frag)
//  - setprio(1) around MFMA clusters
//
// Workspace: pix [8192][128] bf16 @0; W1t [32][256][128] @2MB; W2t [32][256][256] @4MB;
//            W3t [32][16][256] @8MB (rows 4..15 zero).

#define IC    128
#define IHW   1024
#define OCH   32
#define HDIM  256

typedef float  f32x4  __attribute__((ext_vector_type(4)));
typedef float  f32x2  __attribute__((ext_vector_type(2)));
typedef __bf16 bf16x8 __attribute__((ext_vector_type(8)));
typedef unsigned short us8 __attribute__((ext_vector_type(8)));
typedef unsigned int u32;

static __device__ __forceinline__ unsigned short f2bf(float f) {
  __hip_bfloat16 h = __float2bfloat16(f);
  return __builtin_bit_cast(unsigned short, h);
}

static __device__ __forceinline__ u32 cvtpk(float lo, float hi) {
  u32 r;
  asm("v_cvt_pk_bf16_f32 %0, %1, %2" : "=v"(r) : "v"(lo), "v"(hi));
  return r;
}

static __device__ __forceinline__ bf16x8 ld16(const unsigned short* p) {
  return __builtin_bit_cast(bf16x8, *reinterpret_cast<const uint4*>(p));
}

static __device__ __forceinline__ void gl_lds16(const unsigned short* g, char* l) {
  __builtin_amdgcn_global_load_lds(
      (const __attribute__((address_space(1))) u32*)g,
      (__attribute__((address_space(3))) u32*)l,
      16, 0, 0);
}

// ---- coalesced transpose prepass: dst[b][c][r] (bf16) = src[b][r][c] (f32) ----
__global__ __launch_bounds__(256) void transpose_bf16_k(
    const float* __restrict__ src, unsigned short* __restrict__ dst,
    int NR, int NC, int nrt, int nct)
{
  __shared__ float tl[64 * 65];
  const int bid = blockIdx.x;
  const int ct = bid % nct;
  const int rt = (bid / nct) % nrt;
  const int b  = bid / (nct * nrt);
  const int t  = threadIdx.x;

  const float* sb = src + ((size_t)b * NR + (rt << 6)) * NC + (ct << 6);
  const int col = (t & 15) << 2;
  const int rq  = t >> 4;
#pragma unroll
  for (int rr = 0; rr < 4; ++rr) {
    int row = (rr << 4) + rq;
    f32x4 v = *reinterpret_cast<const f32x4*>(sb + row * NC + col);
#pragma unroll
    for (int i = 0; i < 4; ++i) tl[row * 65 + col + i] = v[i];
  }
  __syncthreads();

  unsigned short* db = dst + ((size_t)b * NC + (ct << 6)) * NR + (rt << 6);
  const int r0 = (t & 7) << 3;
  const int cq = t >> 3;
#pragma unroll
  for (int cr = 0; cr < 2; ++cr) {
    int c = (cr << 5) + cq;
    us8 vv;
#pragma unroll
    for (int i = 0; i < 8; ++i) vv[i] = f2bf(tl[(r0 + i) * 65 + c]);
    *reinterpret_cast<us8*>(db + (size_t)c * NR + r0) = vv;
  }
}

__global__ void conv_w3_k(const float* __restrict__ W3, unsigned short* __restrict__ W3t) {
  int idx = blockIdx.x * 256 + threadIdx.x;
  int k = idx & 255;
  int nn = (idx >> 8) & 15;
  int o = idx >> 12;
  W3t[idx] = (nn < 4) ? f2bf(W3[(o * HDIM + k) * 4 + nn]) : (unsigned short)0;
}

// ---- fused 3-layer MLP ----
// Block = 512 thr = 8 waves, (group o, 2 tiles of 64 px). Wave w owns n-rows
// [w*32, w*32+32) (nf=2), W1/W2 resident in VGPR.
// LDS k-major: pix = 4 ks-blocks of [64m][32k] (4KB each) @0;
//              h   = 8 ks-blocks @16384 (ks-block w written by wave w).
// Swizzle: 16B slot index ^= (m&3). Reader slot = lg^(m&3); m&3 == l15&3 ->
// one base register per region, all reads at offset:ks*4096+mf*1024.

#define LD_B_PIX(dst, ks)                                                        \
  _Pragma("unroll")                                                              \
  for (int mf = 0; mf < 4; ++mf)                                                 \
    dst[mf] = *reinterpret_cast<const bf16x8*>(pbase + ((ks) << 12) + (mf << 10));

#define LD_B_H(dst, ks)                                                          \
  _Pragma("unroll")                                                              \
  for (int mf = 0; mf < 4; ++mf)                                                 \
    dst[mf] = *reinterpret_cast<const bf16x8*>(hbase + ((ks) << 12) + (mf << 10));

#define MFMA8(WR, KS, BP)                                                        \
  __builtin_amdgcn_s_setprio(1);                                                 \
  _Pragma("unroll")                                                              \
  for (int nf = 0; nf < 2; ++nf)                                                 \
    _Pragma("unroll")                                                            \
    for (int mf = 0; mf < 4; ++mf)                                               \
      acc[nf][mf] = __builtin_amdgcn_mfma_f32_16x16x32_bf16(WR[nf][KS], BP[mf], acc[nf][mf], 0, 0, 0); \
  __builtin_amdgcn_s_setprio(0);

// h write: wave w owns ks-block w; logical byte-in-row = nf*32+lg*8, phys ^= (m&3)<<4
#define EPILOGUE                                                                 \
  _Pragma("unroll")                                                              \
  for (int nf = 0; nf < 2; ++nf)                                                 \
    _Pragma("unroll")                                                            \
    for (int mf = 0; mf < 4; ++mf) {                                             \
      uint2 hv;                                                                  \
      hv.x = cvtpk(fmaxf(acc[nf][mf][0], 0.f), fmaxf(acc[nf][mf][1], 0.f));      \
      hv.y = cvtpk(fmaxf(acc[nf][mf][2], 0.f), fmaxf(acc[nf][mf][3], 0.f));      \
      *reinterpret_cast<uint2*>((nf ? wb1 : wb0) + (mf << 10)) = hv;             \
    }

#define INIT_ACC(BB)                                                             \
  _Pragma("unroll")                                                              \
  for (int nf = 0; nf < 2; ++nf)                                                 \
    _Pragma("unroll")                                                            \
    for (int mf = 0; mf < 4; ++mf) acc[nf][mf] = BB[nf];

#define STAGE_PIX(PXB)                                                           \
  _Pragma("unroll")                                                              \
  for (int c = 0; c < 2; ++c) {                                                  \
    int slot = (c << 9) + t;                                                     \
    int ksb = slot >> 8, m = (slot >> 2) & 63, sub = slot & 3;                   \
    gl_lds16(pix + (size_t)((PXB) + m) * IC + (ksb << 5) + ((sub ^ (m & 3)) << 3),\
             pb + slot * 16);                                                    \
  }

__global__ __launch_bounds__(512, 2) void fused_mlp_k(
    const unsigned short* __restrict__ pix,
    const unsigned short* __restrict__ W1t,
    const unsigned short* __restrict__ W2t,
    const unsigned short* __restrict__ W3t,
    const float* __restrict__ b1,
    const float* __restrict__ b2,
    const float* __restrict__ b3f,
    float* __restrict__ out)
{
  __shared__ __align__(16) char lds[49152];
  const int t    = threadIdx.x;
  const int lane = t & 63;
  const int w    = t >> 6;                          // 0..7
  const int bx   = blockIdx.x;
  const int o    = ((bx & 7) << 2) | ((bx >> 3) & 3);   // 4 groups per XCD
  const int pixbase = (bx >> 5) << 7;               // 128 px per block (2 tiles)

  const int l15  = lane & 15;
  const int lg   = lane >> 4;
  const int kgrp = lg << 3;
  const int wnb  = w << 5;                          // wave's 32-row n-slice

  char* pb = lds;
  char* hb = lds + 16384;

  // swizzled single-base addresses (mf/ks-invariant; offsets are immediates)
  const int sw = ((lg ^ (l15 & 3)) << 4);
  const char* pbase = pb + (l15 << 6) + sw;
  const char* hbase = hb + (l15 << 6) + sw;
  // epilogue write bases (nf=0/1): phys byte = (nf*32+lg*8) ^ ((l15&3)<<4)
  char* wb0 = hb + (w << 12) + (l15 << 6) + (((lg << 3)) ^ ((l15 & 3) << 4));
  char* wb1 = hb + (w << 12) + (l15 << 6) + ((32 + (lg << 3)) ^ ((l15 & 3) << 4));

  // ---- stage tile-0 pix (async; drains at B0) ----
  STAGE_PIX(pixbase)

  // ---- resident weights (prologue only) ----
  const unsigned short* W1p = W1t + (o << 15) + (wnb + l15) * IC + kgrp;
  const unsigned short* W2p = W2t + (o << 16) + (wnb + l15) * HDIM + kgrp;
  bf16x8 W1r[2][4], W2r[2][8];
#pragma unroll
  for (int nf = 0; nf < 2; ++nf)
#pragma unroll
    for (int ks = 0; ks < 4; ++ks)
      W1r[nf][ks] = ld16(W1p + (nf << 4) * IC + (ks << 5));
#pragma unroll
  for (int nf = 0; nf < 2; ++nf)
#pragma unroll
    for (int ks = 0; ks < 8; ++ks)
      W2r[nf][ks] = ld16(W2p + (nf << 4) * HDIM + (ks << 5));

  // bias fragments (acc-init): row n0 = wnb + nf*16 + lg*4
  f32x4 bb1[2], bb2[2];
#pragma unroll
  for (int nf = 0; nf < 2; ++nf) {
    bb1[nf] = *reinterpret_cast<const f32x4*>(b1 + (o << 8) + wnb + (nf << 4) + (lg << 2));
    bb2[nf] = *reinterpret_cast<const f32x4*>(b2 + (o << 8) + wnb + (nf << 4) + (lg << 2));
  }
  const f32x4 b3v = *reinterpret_cast<const f32x4*>(b3f + (o << 2));

  f32x4 acc[2][4];
  bf16x8 bp[4], bq[4];

  __syncthreads();   // B0: tile-0 pix ready

#pragma unroll
  for (int tt = 0; tt < 2; ++tt) {
    const int base = pixbase + (tt << 6);

    // ================= layer 1: K=128, resident W1 =================
    INIT_ACC(bb1)
    LD_B_PIX(bp, 0)
    LD_B_PIX(bq, 1) MFMA8(W1r, 0, bp)
    LD_B_PIX(bp, 2) MFMA8(W1r, 1, bq)
    LD_B_PIX(bq, 3) MFMA8(W1r, 2, bp)
                    MFMA8(W1r, 3, bq)
    EPILOGUE
    __syncthreads();   // B1: h1 ready; pix reads done

    // restage pix for tile 1 (drains at B2)
    if (tt == 0) { STAGE_PIX(pixbase + 64) }

    // ================= layer 2: K=256, resident W2 =================
    INIT_ACC(bb2)
    LD_B_H(bp, 0)
    LD_B_H(bq, 1) MFMA8(W2r, 0, bp)
    LD_B_H(bp, 2) MFMA8(W2r, 1, bq)
    LD_B_H(bq, 3) MFMA8(W2r, 2, bp)
    LD_B_H(bp, 4) MFMA8(W2r, 3, bq)
    LD_B_H(bq, 5) MFMA8(W2r, 4, bp)
    LD_B_H(bp, 6) MFMA8(W2r, 5, bq)
    LD_B_H(bq, 7) MFMA8(W2r, 6, bp)
                  MFMA8(W2r, 7, bq)
    __syncthreads();   // B2: h1 reads done (+ restage drained)

    EPILOGUE           // h2 overwrites h1 region (same layout)
    __syncthreads();   // B3: h2 ready

    // ===== layer 3: waves 0-3, 16 px each, FULL K, dual accumulators =====
    if (w < 4) {
      const unsigned short* W3p = W3t + (o << 12) + l15 * HDIM + kgrp;
      const char* pL3 = hb + (w << 10) + (l15 << 6) + sw;   // row m3 = w*16+l15
      f32x4 a3a = b3v;
      f32x4 a3b = {0.f, 0.f, 0.f, 0.f};
      bf16x8 w3f0 = ld16(W3p),      w3f1 = ld16(W3p + 32);
      bf16x8 bh0  = *reinterpret_cast<const bf16x8*>(pL3);
      bf16x8 bh1  = *reinterpret_cast<const bf16x8*>(pL3 + 4096);
#pragma unroll
      for (int ks = 0; ks < 8; ks += 2) {
        bf16x8 wnA, bnA, wnB, bnB;
        if (ks < 6) {
          wnA = ld16(W3p + ((ks + 2) << 5));
          bnA = *reinterpret_cast<const bf16x8*>(pL3 + ((ks + 2) << 12));
          wnB = ld16(W3p + ((ks + 3) << 5));
          bnB = *reinterpret_cast<const bf16x8*>(pL3 + ((ks + 3) << 12));
        }
        a3a = __builtin_amdgcn_mfma_f32_16x16x32_bf16(w3f0, bh0, a3a, 0, 0, 0);
        a3b = __builtin_amdgcn_mfma_f32_16x16x32_bf16(w3f1, bh1, a3b, 0, 0, 0);
        w3f0 = wnA; bh0 = bnA; w3f1 = wnB; bh1 = bnB;
      }
      if (lane < 16) {
        int pixel = base + (w << 4) + l15;
        int n = pixel >> 10, p = pixel & 1023;
        int ii = p >> 5, jj = p & 31;
        float* ob = out + ((size_t)((n << 5) + o) << 12) + (ii << 7) + (jj << 1);
        f32x2 r0 = { a3a[0] + a3b[0], a3a[1] + a3b[1] };
        f32x2 r1 = { a3a[2] + a3b[2], a3a[3] + a3b[3] };
        *reinterpret_cast<f32x2*>(ob) = r0;
        *reinterpret_cast<f32x2*>(ob + 64) = r1;
      }
    }
    if (tt == 0) __syncthreads();   // B4: h2 reads done; tile-1 may overwrite hb
  }
}

extern "C" void kernel_launch(void* const* d_in, const int* in_sizes, int n_in,
                              void* d_out, int out_size, void* d_ws, size_t ws_size,
                              hipStream_t stream) {
  const float* x  = (const float*)d_in[0];
  const float* W1 = (const float*)d_in[1];
  const float* b1 = (const float*)d_in[2];
  const float* W2 = (const float*)d_in[3];
  const float* b2 = (const float*)d_in[4];
  const float* W3 = (const float*)d_in[5];
  const float* b3 = (const float*)d_in[6];
  float* out = (float*)d_out;

  char* ws = (char*)d_ws;
  unsigned short* pixw = (unsigned short*)(ws);
  unsigned short* W1t  = (unsigned short*)(ws + (size_t)(2u << 20));
  unsigned short* W2t  = (unsigned short*)(ws + (size_t)(4u << 20));
  unsigned short* W3t  = (unsigned short*)(ws + (size_t)(8u << 20));

  transpose_bf16_k<<<8 * 2 * 16, 256, 0, stream>>>(x, pixw, 128, 1024, 2, 16);
  transpose_bf16_k<<<32 * 2 * 4, 256, 0, stream>>>(W1, W1t, 128, 256, 2, 4);
  transpose_bf16_k<<<32 * 4 * 4, 256, 0, stream>>>(W2, W2t, 256, 256, 4, 4);
  conv_w3_k<<<512, 256, 0, stream>>>(W3, W3t);

  fused_mlp_k<<<2048, 512, 0, stream>>>(pixw, W1t, W2t, W3t, b1, b2, b3, out);
}

// Round 10
// 92.790 us; speedup vs baseline: 1.3731x; 1.3731x over previous
//
#include <hip/hip_runtime.h>
#include <hip/hip_bf16.h>

// DeConv2d = 32 per-channel MLPs (128->256->256->4) over 8192 px + 2x2 shuffle.
//
// R10: all prior structures (R3/R4/R6/R8/R9) land 103-125us with every pipe
// <21% busy -> the invariant is the barrier-chained phase structure (m233
// regime). R10 = cross-layer software pipeline, ONE barrier per iteration:
//   iter i: {stage pix(i+2) | L2(i) | L3(i-1) | L1(i+1)} barrier
// 3 independent chains per region + async stage; 8 tiles x 32 px per block.
// LDS 80KB (pix 2x8K, h1 2x16K, h2 2x16K), 2 blocks/CU, 4 waves/SIMD.
// Registers = R8's clean config (8 waves, nf=2, W1/W2 resident).
// LDS swizzle: row-major + ^((m&7)<<4) (measured-best, 5.77M confl in R1-R3).
//
// Workspace: pix [8192][128] bf16 @0; W1t [32][256][128] @2MB; W2t [32][256][256] @4MB;
//            W3t [32][16][256] @8MB (rows 4..15 zero).

#define IC    128
#define IHW   1024
#define OCH   32
#define HDIM  256

typedef float  f32x4  __attribute__((ext_vector_type(4)));
typedef float  f32x2  __attribute__((ext_vector_type(2)));
typedef __bf16 bf16x8 __attribute__((ext_vector_type(8)));
typedef unsigned short us8 __attribute__((ext_vector_type(8)));
typedef unsigned int u32;

static __device__ __forceinline__ unsigned short f2bf(float f) {
  __hip_bfloat16 h = __float2bfloat16(f);
  return __builtin_bit_cast(unsigned short, h);
}

static __device__ __forceinline__ u32 cvtpk(float lo, float hi) {
  u32 r;
  asm("v_cvt_pk_bf16_f32 %0, %1, %2" : "=v"(r) : "v"(lo), "v"(hi));
  return r;
}

static __device__ __forceinline__ bf16x8 ld16(const unsigned short* p) {
  return __builtin_bit_cast(bf16x8, *reinterpret_cast<const uint4*>(p));
}

static __device__ __forceinline__ void gl_lds16(const unsigned short* g, char* l) {
  __builtin_amdgcn_global_load_lds(
      (const __attribute__((address_space(1))) u32*)g,
      (__attribute__((address_space(3))) u32*)l,
      16, 0, 0);
}

// ---- coalesced transpose prepass: dst[b][c][r] (bf16) = src[b][r][c] (f32) ----
__global__ __launch_bounds__(256) void transpose_bf16_k(
    const float* __restrict__ src, unsigned short* __restrict__ dst,
    int NR, int NC, int nrt, int nct)
{
  __shared__ float tl[64 * 65];
  const int bid = blockIdx.x;
  const int ct = bid % nct;
  const int rt = (bid / nct) % nrt;
  const int b  = bid / (nct * nrt);
  const int t  = threadIdx.x;

  const float* sb = src + ((size_t)b * NR + (rt << 6)) * NC + (ct << 6);
  const int col = (t & 15) << 2;
  const int rq  = t >> 4;
#pragma unroll
  for (int rr = 0; rr < 4; ++rr) {
    int row = (rr << 4) + rq;
    f32x4 v = *reinterpret_cast<const f32x4*>(sb + row * NC + col);
#pragma unroll
    for (int i = 0; i < 4; ++i) tl[row * 65 + col + i] = v[i];
  }
  __syncthreads();

  unsigned short* db = dst + ((size_t)b * NC + (ct << 6)) * NR + (rt << 6);
  const int r0 = (t & 7) << 3;
  const int cq = t >> 3;
#pragma unroll
  for (int cr = 0; cr < 2; ++cr) {
    int c = (cr << 5) + cq;
    us8 vv;
#pragma unroll
    for (int i = 0; i < 8; ++i) vv[i] = f2bf(tl[(r0 + i) * 65 + c]);
    *reinterpret_cast<us8*>(db + (size_t)c * NR + r0) = vv;
  }
}

__global__ void conv_w3_k(const float* __restrict__ W3, unsigned short* __restrict__ W3t) {
  int idx = blockIdx.x * 256 + threadIdx.x;
  int k = idx & 255;
  int nn = (idx >> 8) & 15;
  int o = idx >> 12;
  W3t[idx] = (nn < 4) ? f2bf(W3[(o * HDIM + k) * 4 + nn]) : (unsigned short)0;
}

// ---- fused 3-layer MLP, cross-layer pipelined ----
// Block = 512 thr = 8 waves, (group o, 256 px = 8 tiles of 32). Wave w owns
// n-rows [w*32,w*32+32) (nf=2). Tile M=32 (mf=2).
// D frag: col=lane&15 -> px, row=(lane>>4)*4+reg -> n.

// B-frag loads; ROW = 8 (pix, 256B rows) or 9 (h, 512B rows); m&7 == l15&7.
#define LDB(dst, buf, ROW, ks)                                                   \
  _Pragma("unroll")                                                              \
  for (int mf = 0; mf < 2; ++mf) {                                               \
    int m = (mf << 4) + l15;                                                     \
    dst[mf] = *reinterpret_cast<const bf16x8*>(                                  \
        (buf) + ((((m << (ROW)) + ((ks) << 6) + (kgrp << 1))) ^ ((l15 & 7) << 4)));\
  }

#define MF4(WR, KS, BP)                                                          \
  __builtin_amdgcn_s_setprio(1);                                                 \
  _Pragma("unroll")                                                              \
  for (int nf = 0; nf < 2; ++nf)                                                 \
    _Pragma("unroll")                                                            \
    for (int mf = 0; mf < 2; ++mf)                                               \
      acc[nf][mf] = __builtin_amdgcn_mfma_f32_16x16x32_bf16(WR[nf][KS], BP[mf], acc[nf][mf], 0, 0, 0); \
  __builtin_amdgcn_s_setprio(0);

#define EPI(dst)                                                                 \
  _Pragma("unroll")                                                              \
  for (int nf = 0; nf < 2; ++nf) {                                               \
    int n0 = wnb + (nf << 4) + (lg << 2);                                        \
    _Pragma("unroll")                                                            \
    for (int mf = 0; mf < 2; ++mf) {                                             \
      int m = (mf << 4) + l15;                                                   \
      uint2 hv;                                                                  \
      hv.x = cvtpk(fmaxf(acc[nf][mf][0], 0.f), fmaxf(acc[nf][mf][1], 0.f));      \
      hv.y = cvtpk(fmaxf(acc[nf][mf][2], 0.f), fmaxf(acc[nf][mf][3], 0.f));      \
      *reinterpret_cast<uint2*>(                                                 \
          (dst) + (((m << 9) + (n0 << 1)) ^ ((l15 & 7) << 4))) = hv;             \
    }                                                                            \
  }

#define INIT_ACC(BB)                                                             \
  _Pragma("unroll")                                                              \
  for (int nf = 0; nf < 2; ++nf)                                                 \
    _Pragma("unroll")                                                            \
    for (int mf = 0; mf < 2; ++mf) acc[nf][mf] = BB[nf];

// stage one 32-px tile (8KB): 512 threads x 16B; pre-swizzled source, linear dest
#define STAGE(PXB, BUF)                                                          \
  {                                                                              \
    int m = t >> 4, c16 = t & 15;                                                \
    gl_lds16(pix + (size_t)((PXB) + m) * IC + ((c16 ^ (m & 7)) << 3),            \
             (BUF) + t * 16);                                                    \
  }

__global__ __launch_bounds__(512, 2) void fused_mlp_k(
    const unsigned short* __restrict__ pix,
    const unsigned short* __restrict__ W1t,
    const unsigned short* __restrict__ W2t,
    const unsigned short* __restrict__ W3t,
    const float* __restrict__ b1,
    const float* __restrict__ b2,
    const float* __restrict__ b3f,
    float* __restrict__ out)
{
  __shared__ __align__(16) char lds[81920];
  const int t    = threadIdx.x;
  const int lane = t & 63;
  const int w    = t >> 6;                          // 0..7
  const int bx   = blockIdx.x;
  const int o    = ((bx & 7) << 2) | ((bx >> 3) & 3);   // 4 groups per XCD
  const int pixbase = (bx >> 5) << 8;               // 256 px per block (8 tiles)

  const int l15  = lane & 15;
  const int lg   = lane >> 4;
  const int kgrp = lg << 3;
  const int wnb  = w << 5;

  char* pixb[2] = { lds,         lds + 8192 };
  char* h1b[2]  = { lds + 16384, lds + 32768 };
  char* h2b[2]  = { lds + 49152, lds + 65536 };

  // ---- prologue: stage tiles 0,1; resident weights; biases ----
  STAGE(pixbase,      pixb[0])
  STAGE(pixbase + 32, pixb[1])

  const unsigned short* W1p = W1t + (o << 15) + (wnb + l15) * IC + kgrp;
  const unsigned short* W2p = W2t + (o << 16) + (wnb + l15) * HDIM + kgrp;
  bf16x8 W1r[2][4], W2r[2][8];
#pragma unroll
  for (int nf = 0; nf < 2; ++nf)
#pragma unroll
    for (int ks = 0; ks < 4; ++ks)
      W1r[nf][ks] = ld16(W1p + (nf << 4) * IC + (ks << 5));
#pragma unroll
  for (int nf = 0; nf < 2; ++nf)
#pragma unroll
    for (int ks = 0; ks < 8; ++ks)
      W2r[nf][ks] = ld16(W2p + (nf << 4) * HDIM + (ks << 5));

  f32x4 bb1[2], bb2[2];
#pragma unroll
  for (int nf = 0; nf < 2; ++nf) {
    bb1[nf] = *reinterpret_cast<const f32x4*>(b1 + (o << 8) + wnb + (nf << 4) + (lg << 2));
    bb2[nf] = *reinterpret_cast<const f32x4*>(b2 + (o << 8) + wnb + (nf << 4) + (lg << 2));
  }
  const f32x4 b3v = *reinterpret_cast<const f32x4*>(b3f + (o << 2));

  f32x4 acc[2][2];
  bf16x8 bp[2], bq[2];

  __syncthreads();   // P0: pix tiles 0,1 staged (vmcnt drained)

  // L1(0) -> h1b[0]
  INIT_ACC(bb1)
  LDB(bp, pixb[0], 8, 0)
  LDB(bq, pixb[0], 8, 1) MF4(W1r, 0, bp)
  LDB(bp, pixb[0], 8, 2) MF4(W1r, 1, bq)
  LDB(bq, pixb[0], 8, 3) MF4(W1r, 2, bp)
                         MF4(W1r, 3, bq)
  EPI(h1b[0])
  __syncthreads();   // P1: h1(0) visible

  // ---- main pipeline: iter i = {stage(i+2), L2(i), L3(i-1), L1(i+1)} ----
#pragma unroll
  for (int i = 0; i <= 8; ++i) {
    if (i <= 5) STAGE(pixbase + ((i + 2) << 5), pixb[i & 1])

    if (i <= 7) {   // ===== L2(i): h1b[i&1] -> h2b[i&1] =====
      char* src = h1b[i & 1];
      INIT_ACC(bb2)
      LDB(bp, src, 9, 0)
      LDB(bq, src, 9, 1) MF4(W2r, 0, bp)
      LDB(bp, src, 9, 2) MF4(W2r, 1, bq)
      LDB(bq, src, 9, 3) MF4(W2r, 2, bp)
      LDB(bp, src, 9, 4) MF4(W2r, 3, bq)
      LDB(bq, src, 9, 5) MF4(W2r, 4, bp)
      LDB(bp, src, 9, 6) MF4(W2r, 5, bq)
      LDB(bq, src, 9, 7) MF4(W2r, 6, bp)
                         MF4(W2r, 7, bq)
      EPI(h2b[i & 1])
    }

    if (i >= 1 && w < 2) {   // ===== L3(i-1): h2b[(i-1)&1] -> out (waves 0,1) =====
      const char* hs = h2b[(i - 1) & 1];
      const unsigned short* W3p = W3t + (o << 12) + l15 * HDIM + kgrp;
      const int m3 = (w << 4) + l15;
      f32x4 a3a = b3v;
      f32x4 a3b = {0.f, 0.f, 0.f, 0.f};
      bf16x8 w3f0 = ld16(W3p), w3f1 = ld16(W3p + 32);
      bf16x8 bh0 = *reinterpret_cast<const bf16x8*>(
          hs + (((m3 << 9) + (kgrp << 1)) ^ ((l15 & 7) << 4)));
      bf16x8 bh1 = *reinterpret_cast<const bf16x8*>(
          hs + (((m3 << 9) + (1 << 6) + (kgrp << 1)) ^ ((l15 & 7) << 4)));
#pragma unroll
      for (int ks = 0; ks < 8; ks += 2) {
        bf16x8 wnA, bnA, wnB, bnB;
        if (ks < 6) {
          wnA = ld16(W3p + ((ks + 2) << 5));
          bnA = *reinterpret_cast<const bf16x8*>(
              hs + (((m3 << 9) + ((ks + 2) << 6) + (kgrp << 1)) ^ ((l15 & 7) << 4)));
          wnB = ld16(W3p + ((ks + 3) << 5));
          bnB = *reinterpret_cast<const bf16x8*>(
              hs + (((m3 << 9) + ((ks + 3) << 6) + (kgrp << 1)) ^ ((l15 & 7) << 4)));
        }
        a3a = __builtin_amdgcn_mfma_f32_16x16x32_bf16(w3f0, bh0, a3a, 0, 0, 0);
        a3b = __builtin_amdgcn_mfma_f32_16x16x32_bf16(w3f1, bh1, a3b, 0, 0, 0);
        w3f0 = wnA; bh0 = bnA; w3f1 = wnB; bh1 = bnB;
      }
      if (lane < 16) {
        int pixel = pixbase + ((i - 1) << 5) + m3;
        int n = pixel >> 10, p = pixel & 1023;
        int ii = p >> 5, jj = p & 31;
        float* ob = out + ((size_t)((n << 5) + o) << 12) + (ii << 7) + (jj << 1);
        f32x2 r0 = { a3a[0] + a3b[0], a3a[1] + a3b[1] };
        f32x2 r1 = { a3a[2] + a3b[2], a3a[3] + a3b[3] };
        *reinterpret_cast<f32x2*>(ob) = r0;
        *reinterpret_cast<f32x2*>(ob + 64) = r1;
      }
    }

    if (i <= 6) {   // ===== L1(i+1): pixb[(i+1)&1] -> h1b[(i+1)&1] =====
      char* psrc = pixb[(i + 1) & 1];
      INIT_ACC(bb1)
      LDB(bp, psrc, 8, 0)
      LDB(bq, psrc, 8, 1) MF4(W1r, 0, bp)
      LDB(bp, psrc, 8, 2) MF4(W1r, 1, bq)
      LDB(bq, psrc, 8, 3) MF4(W1r, 2, bp)
                          MF4(W1r, 3, bq)
      EPI(h1b[(i + 1) & 1])
    }

    __syncthreads();   // single barrier per iteration
  }
}

extern "C" void kernel_launch(void* const* d_in, const int* in_sizes, int n_in,
                              void* d_out, int out_size, void* d_ws, size_t ws_size,
                              hipStream_t stream) {
  const float* x  = (const float*)d_in[0];
  const float* W1 = (const float*)d_in[1];
  const float* b1 = (const float*)d_in[2];
  const float* W2 = (const float*)d_in[3];
  const float* b2 = (const float*)d_in[4];
  const float* W3 = (const float*)d_in[5];
  const float* b3 = (const float*)d_in[6];
  float* out = (float*)d_out;

  char* ws = (char*)d_ws;
  unsigned short* pixw = (unsigned short*)(ws);
  unsigned short* W1t  = (unsigned short*)(ws + (size_t)(2u << 20));
  unsigned short* W2t  = (unsigned short*)(ws + (size_t)(4u << 20));
  unsigned short* W3t  = (unsigned short*)(ws + (size_t)(8u << 20));

  transpose_bf16_k<<<8 * 2 * 16, 256, 0, stream>>>(x, pixw, 128, 1024, 2, 16);
  transpose_bf16_k<<<32 * 2 * 4, 256, 0, stream>>>(W1, W1t, 128, 256, 2, 4);
  transpose_bf16_k<<<32 * 4 * 4, 256, 0, stream>>>(W2, W2t, 256, 256, 4, 4);
  conv_w3_k<<<512, 256, 0, stream>>>(W3, W3t);

  fused_mlp_k<<<1024, 512, 0, stream>>>(pixw, W1t, W2t, W3t, b1, b2, b3, out);
}